// Round 4
// baseline (162.145 us; speedup 1.0000x reference)
//
#include <hip/hip_runtime.h>

#define SN 524288   // columns of the (64, SN) view of x

typedef float f32x4 __attribute__((ext_vector_type(4)));

// -------- Kernel P: build C = [B | M21] in LDS, Gauss-Jordan solve, emit A --------
// Single block, 256 threads. Output layout AtW[(h*64 + k)*32 + ii] = A[32h+ii][k]
// (so k_apply's per-(half,k) 32 A-values are contiguous -> scalar dwordx16 loads).
__global__ __launch_bounds__(256) void k_prep(const float* __restrict__ L,
                                              const float* __restrict__ R,
                                              float* __restrict__ AtW) {
  __shared__ float4 Ls[4096];            // L (128x128) XOR-swizzled in float4 units
  __shared__ float Ct[128 * 64];         // Ct[c*64 + i] = C[i][c]
  __shared__ float colbuf[2][64];
  __shared__ __align__(16) float rowbuf[2][128];

  const float4* L4 = (const float4*)L;
  #pragma unroll
  for (int it = 0; it < 16; ++it) {
    int idx = threadIdx.x + it * 256;
    int row = idx >> 5, t4 = idx & 31;
    Ls[(row << 5) + (t4 ^ (row & 7))] = L4[idx];
  }
  __syncthreads();

  // ---- build C (8192 entries, 32 per thread); c uniform per wave, i = lane ----
  #pragma unroll
  for (int it = 0; it < 32; ++it) {
    int g = it * 256 + threadIdx.x;
    int c = g >> 6;
    int i = g & 63;
    if (c < 64) {
      float d1 = 0.f, d2 = 0.f;
      #pragma unroll
      for (int t4 = 0; t4 < 32; ++t4) {
        float4 a1 = Ls[(i << 5) + (t4 ^ (i & 7))];
        float4 b1 = Ls[(c << 5) + (t4 ^ (c & 7))];
        float4 a2 = Ls[((64 + i) << 5) + (t4 ^ (i & 7))];
        float4 b2 = Ls[((64 + c) << 5) + (t4 ^ (c & 7))];
        d1 += a1.x * b1.x + a1.y * b1.y + a1.z * b1.z + a1.w * b1.w;
        d2 += a2.x * b2.x + a2.y * b2.y + a2.z * b2.z + a2.w * b2.w;
      }
      float val = 2.0f * (d1 + d2 + R[i * 64 + c] - R[c * 64 + i]);
      if (i == c) val += 4e-8f;
      Ct[c * 64 + i] = val;
    } else {
      int jj = c - 64;
      float d = 0.f;
      #pragma unroll
      for (int t4 = 0; t4 < 32; ++t4) {
        float4 a = Ls[(i << 5) + (t4 ^ (i & 7))];
        float4 b = Ls[((64 + jj) << 5) + (t4 ^ (jj & 7))];
        d += a.x * b.x + a.y * b.y + a.z * b.z + a.w * b.w;
      }
      Ct[c * 64 + i] = d;
    }
  }
  __syncthreads();

  // ---- Gauss-Jordan: rows in lanes, 32 columns per thread in registers ----
  const int r = threadIdx.x & 63;
  const int cgrp = threadIdx.x >> 6;
  float creg[32];
  #pragma unroll
  for (int cc = 0; cc < 32; ++cc)
    creg[cc] = Ct[(cgrp * 32 + cc) * 64 + r];
  #pragma unroll
  for (int p = 0; p < 64; ++p) {
    const int pb = p & 1, pc = p >> 5, pi = p & 31;
    if (cgrp == pc) colbuf[pb][r] = creg[pi];
    if (r == p) {
      #pragma unroll
      for (int cc = 0; cc < 32; ++cc) rowbuf[pb][cgrp * 32 + cc] = creg[cc];
    }
    __syncthreads();
    const float f = colbuf[pb][r];
    const float inv = 1.0f / colbuf[pb][p];
    if (r == p) {
      #pragma unroll
      for (int cc = 0; cc < 32; ++cc) creg[cc] *= inv;
    } else {
      const float gg = f * inv;
      #pragma unroll
      for (int c4 = 0; c4 < 8; ++c4) {
        const float4 pv = *(const float4*)&rowbuf[pb][cgrp * 32 + c4 * 4];
        creg[c4 * 4 + 0] -= gg * pv.x;
        creg[c4 * 4 + 1] -= gg * pv.y;
        creg[c4 * 4 + 2] -= gg * pv.z;
        creg[c4 * 4 + 3] -= gg * pv.w;
      }
    }
  }
  // creg[cc] (cgrp>=2) = A[r][(cgrp-2)*32+cc]; write AtW[((r>>5)*64+k)*32 + (r&31)]
  if (cgrp >= 2) {
    #pragma unroll
    for (int cc = 0; cc < 32; ++cc) {
      int k = (cgrp - 2) * 32 + cc;
      AtW[((r >> 5) * 64 + k) * 32 + (r & 31)] = creg[cc];
    }
  }
}

// -------- Kernel C: out = A @ X, X = x viewed (64, SN) --------
// No LDS. 4 waves/block: wave w -> i-half h=w>>1 (rows 32h..32h+31), j-window jw=w&1.
// A comes through the scalar pipe (uniform base via readfirstlane -> s_load),
// FMAs use SGPR src0. x: 4-deep rolling prefetch, dword-coalesced.
__global__ __launch_bounds__(256) void k_apply(const float* __restrict__ x,
                                               const float* __restrict__ AtW,
                                               float* __restrict__ out) {
  const int lane = threadIdx.x & 63;
  const int wv = threadIdx.x >> 6;
  const int jw = wv & 1;
  const int h = __builtin_amdgcn_readfirstlane(wv >> 1);  // uniform i-half
  const int c = blockIdx.x * 128 + jw * 64 + lane;        // dword column of x/out
  const float* __restrict__ Ab = AtW + h * 64 * 32;       // Ab[k*32+ii] = A[32h+ii][k]

  float acc[32];
  #pragma unroll
  for (int i = 0; i < 32; ++i) acc[i] = 0.f;

  const float* xc = x + c;
  float xb[4];
  #pragma unroll
  for (int d = 0; d < 4; ++d) xb[d] = xc[d * SN];

  #pragma unroll 4
  for (int k = 0; k < 64; ++k) {
    const float xv = xb[k & 3];
    const int kp = (k + 4 < 64) ? (k + 4) : 63;  // clamped prefetch
    xb[k & 3] = xc[kp * SN];
    const float* __restrict__ ak = Ab + k * 32;  // uniform address
    #pragma unroll
    for (int i = 0; i < 32; ++i)
      acc[i] = fmaf(ak[i], xv, acc[i]);
  }

  float* oc = out + (h * 32) * SN + c;
  #pragma unroll
  for (int i = 0; i < 32; ++i)
    oc[i * SN] = acc[i];
}

extern "C" void kernel_launch(void* const* d_in, const int* in_sizes, int n_in,
                              void* d_out, int out_size, void* d_ws, size_t ws_size,
                              hipStream_t stream) {
  const float* x = (const float*)d_in[0];  // 524288 x 64
  const float* L = (const float*)d_in[1];  // 128 x 128
  const float* R = (const float*)d_in[2];  // 64 x 64
  float* out = (float*)d_out;
  float* AtW = (float*)d_ws;               // 64*64 f32 = 16 KB
  k_prep<<<1, 256, 0, stream>>>(L, R, AtW);
  k_apply<<<4096, 256, 0, stream>>>(x, AtW, out);
}

// Round 5
// 101.016 us; speedup vs baseline: 1.6051x; 1.6051x over previous
//
#include <hip/hip_runtime.h>

#define SN 524288   // columns of the (64, SN) view of x

typedef float f32x4 __attribute__((ext_vector_type(4)));

// ---------------- Kernel A: build Ct[c*64 + i] = C[i][c], C = [B | M21] (64 x 128) ---
__global__ __launch_bounds__(256) void k_buildC(const float* __restrict__ L,
                                                const float* __restrict__ R,
                                                float* __restrict__ Ct) {
  __shared__ float4 Ls[4096];  // L (128x128) XOR-swizzled in float4 units
  const float4* L4 = (const float4*)L;
  #pragma unroll
  for (int it = 0; it < 16; ++it) {
    int idx = threadIdx.x + it * 256;
    int row = idx >> 5, t4 = idx & 31;
    Ls[(row << 5) + (t4 ^ (row & 7))] = L4[idx];
  }
  __syncthreads();
  int g = blockIdx.x * 256 + threadIdx.x;  // 0..8191
  int c = g >> 6;                          // column of C, uniform per wave
  int i = g & 63;                          // row of C = lane
  if (c < 64) {
    float d1 = 0.f, d2 = 0.f;
    #pragma unroll
    for (int t4 = 0; t4 < 32; ++t4) {
      float4 a1 = Ls[(i << 5) + (t4 ^ (i & 7))];
      float4 b1 = Ls[(c << 5) + (t4 ^ (c & 7))];
      float4 a2 = Ls[((64 + i) << 5) + (t4 ^ (i & 7))];
      float4 b2 = Ls[((64 + c) << 5) + (t4 ^ (c & 7))];
      d1 += a1.x * b1.x + a1.y * b1.y + a1.z * b1.z + a1.w * b1.w;
      d2 += a2.x * b2.x + a2.y * b2.y + a2.z * b2.z + a2.w * b2.w;
    }
    float val = 2.0f * (d1 + d2 + R[i * 64 + c] - R[c * 64 + i]);
    if (i == c) val += 4e-8f;
    Ct[c * 64 + i] = val;
  } else {
    int jj = c - 64;
    float d = 0.f;
    #pragma unroll
    for (int t4 = 0; t4 < 32; ++t4) {
      float4 a = Ls[(i << 5) + (t4 ^ (i & 7))];
      float4 b = Ls[((64 + jj) << 5) + (t4 ^ (jj & 7))];
      d += a.x * b.x + a.y * b.y + a.z * b.z + a.w * b.w;
    }
    Ct[c * 64 + i] = d;
  }
}

// ---------------- Kernel B: Gauss-Jordan solve B A = M21 --------------------------
// Emits AtW[(h*64 + k)*32 + ii] = A[32h + ii][k]  (k_apply's scalar-load layout).
__global__ __launch_bounds__(256) void k_solve(const float* __restrict__ Ct,
                                               float* __restrict__ AtW) {
  __shared__ float colbuf[2][64];
  __shared__ __align__(16) float rowbuf[2][128];
  const int r = threadIdx.x & 63;
  const int cgrp = threadIdx.x >> 6;
  float creg[32];
  #pragma unroll
  for (int cc = 0; cc < 32; ++cc)
    creg[cc] = Ct[(cgrp * 32 + cc) * 64 + r];
  #pragma unroll
  for (int p = 0; p < 64; ++p) {
    const int pb = p & 1, pc = p >> 5, pi = p & 31;
    if (cgrp == pc) colbuf[pb][r] = creg[pi];
    if (r == p) {
      #pragma unroll
      for (int cc = 0; cc < 32; ++cc) rowbuf[pb][cgrp * 32 + cc] = creg[cc];
    }
    __syncthreads();
    const float f = colbuf[pb][r];
    const float inv = 1.0f / colbuf[pb][p];
    if (r == p) {
      #pragma unroll
      for (int cc = 0; cc < 32; ++cc) creg[cc] *= inv;
    } else {
      const float gg = f * inv;
      #pragma unroll
      for (int c4 = 0; c4 < 8; ++c4) {
        const float4 pv = *(const float4*)&rowbuf[pb][cgrp * 32 + c4 * 4];
        creg[c4 * 4 + 0] -= gg * pv.x;
        creg[c4 * 4 + 1] -= gg * pv.y;
        creg[c4 * 4 + 2] -= gg * pv.z;
        creg[c4 * 4 + 3] -= gg * pv.w;
      }
    }
  }
  // creg[cc] (cgrp>=2) = A[r][k=(cgrp-2)*32+cc]
  if (cgrp >= 2) {
    #pragma unroll
    for (int cc = 0; cc < 32; ++cc) {
      int k = (cgrp - 2) * 32 + cc;
      AtW[((r >> 5) * 64 + k) * 32 + (r & 31)] = creg[cc];
    }
  }
}

// -------- Kernel C: out = A @ X, X = x viewed (64, SN) --------
// No LDS. 4 waves/block: wave w -> i-half h=w>>1 (rows 32h..32h+31), j-window jw=w&1.
// A comes through the scalar pipe (uniform base via readfirstlane -> s_load),
// FMAs use SGPR src0. x: 4-deep rolling prefetch, dword-coalesced.
__global__ __launch_bounds__(256) void k_apply(const float* __restrict__ x,
                                               const float* __restrict__ AtW,
                                               float* __restrict__ out) {
  const int lane = threadIdx.x & 63;
  const int wv = threadIdx.x >> 6;
  const int jw = wv & 1;
  const int h = __builtin_amdgcn_readfirstlane(wv >> 1);  // uniform i-half
  const int c = blockIdx.x * 128 + jw * 64 + lane;        // dword column of x/out
  const float* __restrict__ Ab = AtW + h * 64 * 32;       // Ab[k*32+ii] = A[32h+ii][k]

  float acc[32];
  #pragma unroll
  for (int i = 0; i < 32; ++i) acc[i] = 0.f;

  const float* xc = x + c;
  float xb[4];
  #pragma unroll
  for (int d = 0; d < 4; ++d) xb[d] = xc[d * SN];

  #pragma unroll 4
  for (int k = 0; k < 64; ++k) {
    const float xv = xb[k & 3];
    const int kp = (k + 4 < 64) ? (k + 4) : 63;  // clamped prefetch
    xb[k & 3] = xc[kp * SN];
    const float* __restrict__ ak = Ab + k * 32;  // uniform address
    #pragma unroll
    for (int i = 0; i < 32; ++i)
      acc[i] = fmaf(ak[i], xv, acc[i]);
  }

  float* oc = out + (h * 32) * SN + c;
  #pragma unroll
  for (int i = 0; i < 32; ++i)
    oc[i * SN] = acc[i];
}

extern "C" void kernel_launch(void* const* d_in, const int* in_sizes, int n_in,
                              void* d_out, int out_size, void* d_ws, size_t ws_size,
                              hipStream_t stream) {
  const float* x = (const float*)d_in[0];  // 524288 x 64
  const float* L = (const float*)d_in[1];  // 128 x 128
  const float* R = (const float*)d_in[2];  // 64 x 64
  float* out = (float*)d_out;
  float* Ct  = (float*)d_ws;               // 128*64 f32 = 32 KB
  float* AtW = Ct + 128 * 64;              // 64*64 f32 = 16 KB
  k_buildC<<<32, 256, 0, stream>>>(L, R, Ct);
  k_solve<<<1, 256, 0, stream>>>(Ct, AtW);
  k_apply<<<4096, 256, 0, stream>>>(x, AtW, out);
}